// Round 1
// baseline (1010.286 us; speedup 1.0000x reference)
//
#include <hip/hip_runtime.h>
#include <hip/hip_bf16.h>

typedef __attribute__((ext_vector_type(8))) short bf16x8;
typedef __attribute__((ext_vector_type(4))) float f32x4;

__device__ __forceinline__ float bf2f(short u) {
  union { unsigned int u; float f; } c;
  c.u = ((unsigned int)(unsigned short)u) << 16;
  return c.f;
}
__device__ __forceinline__ short f2bf(float f) {
  union { float f; unsigned int u; } c; c.f = f;
  unsigned int r = (c.u + 0x7fffu + ((c.u >> 16) & 1u)) >> 16;
  return (short)(unsigned short)r;
}

__device__ __forceinline__ void gload16(const void* g, void* l) {
  __builtin_amdgcn_global_load_lds(
      (const __attribute__((address_space(1))) unsigned int*)g,
      (__attribute__((address_space(3))) unsigned int*)l, 16, 0, 0);
}

// ---------------- fp32 -> bf16 convert ----------------
__global__ __launch_bounds__(256) void cvt_k(const float* __restrict__ in,
                                             short* __restrict__ out, int n4) {
  int i = blockIdx.x * blockDim.x + threadIdx.x;
  const int stride = gridDim.x * blockDim.x;
  for (; i < n4; i += stride) {
    float4 v = ((const float4*)in)[i];
    short4 o;
    o.x = f2bf(v.x); o.y = f2bf(v.y); o.z = f2bf(v.z); o.w = f2bf(v.w);
    ((short4*)out)[i] = o;
  }
}

// ---------------- W [1024][1024] f32 -> W^T bf16 ----------------
__global__ __launch_bounds__(256) void cvtT_k(const float* __restrict__ W,
                                              short* __restrict__ Wt) {
  __shared__ float tile[32][33];
  const int n0 = blockIdx.x * 32, k0 = blockIdx.y * 32;
  const int tr = threadIdx.x >> 5;   // 0..7
  const int tc = threadIdx.x & 31;
#pragma unroll
  for (int p = 0; p < 4; ++p)
    tile[p * 8 + tr][tc] = W[(long long)(k0 + p * 8 + tr) * 1024 + n0 + tc];
  __syncthreads();
#pragma unroll
  for (int p = 0; p < 4; ++p)
    Wt[(long long)(n0 + p * 8 + tr) * 1024 + k0 + tc] = f2bf(tile[tc][p * 8 + tr]);
}

// ---------------- 128x128x32 bf16 MFMA GEMM ----------------
// C[m][n] = sum_k A[m][k] * Bt[n][k]   (both operands K-contiguous row-major)
// EPI 0: bf16 out + bias[col]          (projections)
// EPI 1: bf16 out * scale              (QK^T logits)
// EPI 2: f32 out + X[row*ldc+col]      (PV + residual)
// EPI 3: bf16 out to V^T layout [b][f][s], bias[row]  (V projection, swapped roles)
#define BM 128
#define BN 128
#define BK 32

template<int EPI>
__global__ __launch_bounds__(256) void gemm_k(
    const short* __restrict__ A, const short* __restrict__ Bt,
    void* __restrict__ Cv, const float* __restrict__ X,
    int K, int lda, int ldb, int ldc,
    long long sA, long long sB, long long sC, long long sX, float scale) {
  __shared__ __align__(16) short As[BM * BK];
  __shared__ __align__(16) short Bs[BN * BK];

  const int t = threadIdx.x;
  const int w = t >> 6;
  const int lane = t & 63;
  const int bz = blockIdx.z;
  const int n0 = blockIdx.x * BN;
  const int m0 = blockIdx.y * BM;

  const short* Ab = A + (long long)bz * sA;
  const short* Bb = Bt + (long long)bz * sB;

  const int rA = t >> 2;            // 0..63
  const int kO = (t & 3) * 8;       // k element offset within tile
  const long long ldaL = lda, ldbL = ldb;
  const short* gA = Ab + (long long)(m0 + rA) * ldaL + kO;
  const short* gB = Bb + (long long)(n0 + rA) * ldbL + kO;

  short* sAw = As + w * 512;   // wave-uniform LDS stage base (shorts)
  short* sBw = Bs + w * 512;

  const int wr = w >> 1, wc = w & 1;
  const int l16 = lane & 15;
  const int kq = (lane >> 4) * 8;
  const short* fA = As + (wr * 64 + l16) * BK + kq;
  const short* fB = Bs + (wc * 64 + l16) * BK + kq;

  f32x4 acc[4][4] = {};

  for (int kb = 0; kb < K; kb += BK) {
    gload16(gA,              sAw);
    gload16(gA + 64 * ldaL,  sAw + 2048);
    gload16(gB,              sBw);
    gload16(gB + 64 * ldbL,  sBw + 2048);
    __syncthreads();   // drains vmcnt before any wave reads LDS
    bf16x8 af[4], bfr[4];
#pragma unroll
    for (int i = 0; i < 4; ++i) af[i]  = *(const bf16x8*)(fA + i * 16 * BK);
#pragma unroll
    for (int i = 0; i < 4; ++i) bfr[i] = *(const bf16x8*)(fB + i * 16 * BK);
#pragma unroll
    for (int mi = 0; mi < 4; ++mi)
#pragma unroll
      for (int ni = 0; ni < 4; ++ni)
        acc[mi][ni] = __builtin_amdgcn_mfma_f32_16x16x32_bf16(
            af[mi], bfr[ni], acc[mi][ni], 0, 0, 0);
    __syncthreads();   // LDS consumed; safe to restage next iter
    gA += BK; gB += BK;
  }

  const int colBase = n0 + wc * 64 + l16;
  const int rowBase = m0 + wr * 64 + (lane >> 4) * 4;

  if (EPI == 0) {
    short* C = (short*)Cv + (long long)bz * sC;
#pragma unroll
    for (int ni = 0; ni < 4; ++ni) {
      const int col = colBase + ni * 16;
      const float bv = X[col];
#pragma unroll
      for (int mi = 0; mi < 4; ++mi)
#pragma unroll
        for (int r = 0; r < 4; ++r) {
          const int row = rowBase + mi * 16 + r;
          C[(long long)row * ldc + col] = f2bf(acc[mi][ni][r] + bv);
        }
    }
  } else if (EPI == 1) {
    short* C = (short*)Cv + (long long)bz * sC;
#pragma unroll
    for (int ni = 0; ni < 4; ++ni) {
      const int col = colBase + ni * 16;
#pragma unroll
      for (int mi = 0; mi < 4; ++mi)
#pragma unroll
        for (int r = 0; r < 4; ++r) {
          const int row = rowBase + mi * 16 + r;
          C[(long long)row * ldc + col] = f2bf(acc[mi][ni][r] * scale);
        }
    }
  } else if (EPI == 2) {
    float* C = (float*)Cv + (long long)bz * sC;
    const float* Xb = X + (long long)bz * sX;
#pragma unroll
    for (int ni = 0; ni < 4; ++ni) {
      const int col = colBase + ni * 16;
#pragma unroll
      for (int mi = 0; mi < 4; ++mi)
#pragma unroll
        for (int r = 0; r < 4; ++r) {
          const int row = rowBase + mi * 16 + r;
          const long long idx = (long long)row * ldc + col;
          C[idx] = acc[mi][ni][r] + Xb[idx];
        }
    }
  } else {  // EPI == 3: C = V^T, laid out [b][f=row][s], n = b*2048 + s
    short* C = (short*)Cv;
#pragma unroll
    for (int ni = 0; ni < 4; ++ni) {
      const int col = colBase + ni * 16;
      const int bb = col >> 11;
      const int s = col & 2047;
#pragma unroll
      for (int mi = 0; mi < 4; ++mi)
#pragma unroll
        for (int r = 0; r < 4; ++r) {
          const int row = rowBase + mi * 16 + r;  // f index
          C[(long long)bb * 2097152 + (long long)row * 2048 + s] =
              f2bf(acc[mi][ni][r] + X[row]);
        }
    }
  }
}

// ---------------- row softmax over 2048 (in-place, bf16) ----------------
__global__ __launch_bounds__(256) void softmax_k(short* __restrict__ P) {
  __shared__ float redm[4];
  __shared__ float reds[4];
  const long long row = blockIdx.x;
  short* p = P + row * 2048;
  const int t = threadIdx.x;
  const int w = t >> 6, lane = t & 63;
  bf16x8 v = *(const bf16x8*)(p + t * 8);
  float f[8];
  float mx = -3.0e38f;
#pragma unroll
  for (int j = 0; j < 8; ++j) { f[j] = bf2f(v[j]); mx = fmaxf(mx, f[j]); }
#pragma unroll
  for (int o = 32; o > 0; o >>= 1) mx = fmaxf(mx, __shfl_xor(mx, o));
  if (lane == 0) redm[w] = mx;
  __syncthreads();
  mx = fmaxf(fmaxf(redm[0], redm[1]), fmaxf(redm[2], redm[3]));
  float s = 0.f;
#pragma unroll
  for (int j = 0; j < 8; ++j) { f[j] = __expf(f[j] - mx); s += f[j]; }
#pragma unroll
  for (int o = 32; o > 0; o >>= 1) s += __shfl_xor(s, o);
  if (lane == 0) reds[w] = s;
  __syncthreads();
  s = reds[0] + reds[1] + reds[2] + reds[3];
  const float inv = 1.0f / (s + 1e-6f);
  bf16x8 o8;
#pragma unroll
  for (int j = 0; j < 8; ++j) o8[j] = f2bf(f[j] * inv);
  *(bf16x8*)(p + t * 8) = o8;
}

extern "C" void kernel_launch(void* const* d_in, const int* in_sizes, int n_in,
                              void* d_out, int out_size, void* d_ws, size_t ws_size,
                              hipStream_t stream) {
  const float* x  = (const float*)d_in[0];
  const float* y  = (const float*)d_in[1];
  const float* Wq = (const float*)d_in[2];
  const float* bq = (const float*)d_in[3];
  const float* Wk = (const float*)d_in[4];
  const float* bk = (const float*)d_in[5];
  const float* Wv = (const float*)d_in[6];
  const float* bv = (const float*)d_in[7];
  float* out = (float*)d_out;

  const long long SD  = 2048LL * 1024;       // 2,097,152
  const long long BSD = 16LL * SD;           // 33,554,432
  const long long SS  = 2048LL * 2048;       // 4,194,304

  char* ws = (char*)d_ws;
  short* xb  = (short*)ws;                   // 67.1 MB
  short* yb  = xb + BSD;                     // 67.1 MB
  short* Sl  = (short*)ws;                   // 134.2 MB (aliases xb+yb, written after they die)
  short* Qb  = (short*)(ws + 134217728);     // 67.1 MB
  short* Kb  = Qb + BSD;                     // 67.1 MB
  short* Vt  = Kb + BSD;                     // 67.1 MB  [b][d][s]
  short* Wqt = Vt + BSD;                     // 2 MB each
  short* Wkt = Wqt + 1024 * 1024;
  short* Wvt = Wkt + 1024 * 1024;

  // 1) convert x, y to bf16
  cvt_k<<<2048, 256, 0, stream>>>(x, xb, (int)(BSD / 4));
  cvt_k<<<2048, 256, 0, stream>>>(y, yb, (int)(BSD / 4));

  // 2) transpose+convert weights
  cvtT_k<<<dim3(32, 32), 256, 0, stream>>>(Wq, Wqt);
  cvtT_k<<<dim3(32, 32), 256, 0, stream>>>(Wk, Wkt);
  cvtT_k<<<dim3(32, 32), 256, 0, stream>>>(Wv, Wvt);

  // 3) Q = xb @ Wq + bq   (M=32768, N=1024, K=1024) -> bf16 [s][f]
  gemm_k<0><<<dim3(8, 256, 1), 256, 0, stream>>>(
      xb, Wqt, Qb, bq, 1024, 1024, 1024, 1024, 0, 0, 0, 0, 1.f);
  // 4) K = yb @ Wk + bk
  gemm_k<0><<<dim3(8, 256, 1), 256, 0, stream>>>(
      yb, Wkt, Kb, bk, 1024, 1024, 1024, 1024, 0, 0, 0, 0, 1.f);
  // 5) V^T directly: A = Wv^T (M=1024=f), Bt = yb (N=32768), C -> Vt[b][f][s]
  gemm_k<3><<<dim3(256, 8, 1), 256, 0, stream>>>(
      Wvt, yb, Vt, bv, 1024, 1024, 1024, 0, 0, 0, 0, 0, 1.f);

  // 6) logits = Q @ K^T / 32  (batched 16x: M=N=2048, K=1024) -> bf16, overwrites xb/yb region
  gemm_k<1><<<dim3(16, 16, 16), 256, 0, stream>>>(
      Qb, Kb, Sl, nullptr, 1024, 1024, 1024, 2048, SD, SD, SS, 0, 0.03125f);

  // 7) softmax rows (32768 rows of 2048), in-place
  softmax_k<<<32768, 256, 0, stream>>>(Sl);

  // 8) out = P @ V + x  (batched 16x: M=2048, N=1024, K=2048) -> f32
  gemm_k<2><<<dim3(8, 16, 16), 256, 0, stream>>>(
      Sl, Vt, out, x, 2048, 2048, 2048, 1024, SS, SD, SD, SD, 1.f);

  (void)in_sizes; (void)n_in; (void)out_size; (void)ws_size;
}

// Round 2
// 800.352 us; speedup vs baseline: 1.2623x; 1.2623x over previous
//
#include <hip/hip_runtime.h>
#include <hip/hip_bf16.h>

typedef __attribute__((ext_vector_type(8))) short bf16x8;
typedef __attribute__((ext_vector_type(4))) float f32x4;

__device__ __forceinline__ float bf2f(short u) {
  union { unsigned int u; float f; } c;
  c.u = ((unsigned int)(unsigned short)u) << 16;
  return c.f;
}
__device__ __forceinline__ short f2bf(float f) {
  union { float f; unsigned int u; } c; c.f = f;
  unsigned int r = (c.u + 0x7fffu + ((c.u >> 16) & 1u)) >> 16;
  return (short)(unsigned short)r;
}

__device__ __forceinline__ void gload16(const void* g, void* l) {
  __builtin_amdgcn_global_load_lds(
      (const __attribute__((address_space(1))) unsigned int*)g,
      (__attribute__((address_space(3))) unsigned int*)l, 16, 0, 0);
}

// ---------------- fp32 -> bf16 convert ----------------
__global__ __launch_bounds__(256) void cvt_k(const float* __restrict__ in,
                                             short* __restrict__ out, int n4) {
  int i = blockIdx.x * blockDim.x + threadIdx.x;
  const int stride = gridDim.x * blockDim.x;
  for (; i < n4; i += stride) {
    float4 v = ((const float4*)in)[i];
    short4 o;
    o.x = f2bf(v.x); o.y = f2bf(v.y); o.z = f2bf(v.z); o.w = f2bf(v.w);
    ((short4*)out)[i] = o;
  }
}

// ---------------- W [1024][1024] f32 -> W^T bf16 ----------------
__global__ __launch_bounds__(256) void cvtT_k(const float* __restrict__ W,
                                              short* __restrict__ Wt) {
  __shared__ float tile[32][33];
  const int n0 = blockIdx.x * 32, k0 = blockIdx.y * 32;
  const int tr = threadIdx.x >> 5;
  const int tc = threadIdx.x & 31;
#pragma unroll
  for (int p = 0; p < 4; ++p)
    tile[p * 8 + tr][tc] = W[(long long)(k0 + p * 8 + tr) * 1024 + n0 + tc];
  __syncthreads();
#pragma unroll
  for (int p = 0; p < 4; ++p)
    Wt[(long long)(n0 + p * 8 + tr) * 1024 + k0 + tc] = f2bf(tile[tc][p * 8 + tr]);
}

// =====================================================================
// 256x256x64 8-phase bf16 MFMA GEMM (m201-style template, plain HIP)
//   C[m][n] = sum_k A[m][k] * Bt[n][k]
// 8 waves (2M x 4N), per-wave out 128x64, 4 quadrant-phases per K-tile,
// double-buffered 128KiB LDS, counted vmcnt(4), XOR-16B-slot swizzle.
// EPI 0: bf16 out + bias[col]; 1: bf16 out*scale; 2: f32 out + X[idx];
// EPI 3: bf16 out to V^T layout [b][f=row][s], bias[row].
// =====================================================================

#define STG(sp, ld8, dOff) do { \
  gload16((sp), Ls + (dOff)); \
  gload16((const char*)(sp) + (ld8), Ls + (dOff) + 512); } while (0)

#define DO_PHASE(QM, QN, STAGES, VM) do { \
  bf16x8 af[4][2], bq[2][2]; \
  _Pragma("unroll") \
  for (int mi = 0; mi < 4; ++mi) { \
    af[mi][0] = *(const bf16x8*)(Ls + bufS + (QM)*8192 + arow + mi*1024 + aO0); \
    af[mi][1] = *(const bf16x8*)(Ls + bufS + (QM)*8192 + arow + mi*1024 + aO1); \
  } \
  _Pragma("unroll") \
  for (int ni = 0; ni < 2; ++ni) { \
    bq[ni][0] = *(const bf16x8*)(Ls + bufS + 16384 + (QN)*8192 + brow + ni*1024 + aO0); \
    bq[ni][1] = *(const bf16x8*)(Ls + bufS + 16384 + (QN)*8192 + brow + ni*1024 + aO1); \
  } \
  STAGES; \
  __builtin_amdgcn_sched_barrier(0); \
  __builtin_amdgcn_s_barrier(); \
  asm volatile("s_waitcnt lgkmcnt(0)" ::: "memory"); \
  __builtin_amdgcn_sched_barrier(0); \
  __builtin_amdgcn_s_setprio(1); \
  _Pragma("unroll") \
  for (int mi = 0; mi < 4; ++mi) { \
    _Pragma("unroll") \
    for (int ni = 0; ni < 2; ++ni) { \
      acc[QM][QN][mi][ni] = __builtin_amdgcn_mfma_f32_16x16x32_bf16(af[mi][0], bq[ni][0], acc[QM][QN][mi][ni], 0, 0, 0); \
      acc[QM][QN][mi][ni] = __builtin_amdgcn_mfma_f32_16x16x32_bf16(af[mi][1], bq[ni][1], acc[QM][QN][mi][ni], 0, 0, 0); \
    } \
  } \
  __builtin_amdgcn_s_setprio(0); \
  VM; \
  __builtin_amdgcn_s_barrier(); \
} while (0)

template<int EPI>
__global__ __launch_bounds__(512) void gemm8_k(
    const short* __restrict__ A, const short* __restrict__ Bt,
    void* __restrict__ Cv, const float* __restrict__ X,
    int K, int lda, int ldb, int ldc,
    long long sA, long long sB, long long sC, long long sX, float scale) {
  __shared__ __align__(16) short Ls[65536];   // 128 KiB: 2 buf x (A 16K + B 16K) shorts

  const int lane = threadIdx.x & 63;
  const int w = threadIdx.x >> 6;       // 0..7
  const int wm = w >> 2, wn = w & 3;
  const int w1k = w * 1024;
  const int l15 = lane & 15;
  const int g4 = lane >> 4;             // 0..3
  const int p8 = lane & 7;
  const int r8 = lane >> 3;             // 0..7
  const int aO0 = (g4 ^ p8) << 3;       // kk=0 swizzled 16B-slot (shorts)
  const int aO1 = ((4 + g4) ^ p8) << 3; // kk=1
  const int arow = (wm * 64 + l15) * 64;
  const int brow = (wn * 32 + l15) * 64;

  const int bz = blockIdx.z;
  const int n0 = blockIdx.x * 256;
  const int m0 = blockIdx.y * 256;
  const int nt = K >> 6;

  const long long ldaB = 2LL * lda, ldbB = 2LL * ldb;
  const long long ldaB8 = 8 * ldaB, ldbB8 = 8 * ldbB;
  const long long hOffA = 128 * ldaB, hOffB = 128 * ldbB;

  // per-lane pre-swizzled staging source pointers (dest stays linear)
  const char* pA = (const char*)(A + (long long)bz * sA)
      + (long long)(m0 + w * 16 + r8) * ldaB + ((p8 ^ r8) << 4);
  const char* pB = (const char*)(Bt + (long long)bz * sB)
      + (long long)(n0 + w * 16 + r8) * ldbB + ((p8 ^ r8) << 4);

  f32x4 acc[2][2][4][2] = {};

  // ---- prologue: tile0 all 4 halves + A0,B0 of tile1 ----
  STG(pA,          ldaB8, 0 + w1k);                // buf0.A0(0)
  STG(pA + hOffA,  ldaB8, 8192 + w1k);             // buf0.A1(0)
  STG(pB,          ldbB8, 16384 + w1k);            // buf0.B0(0)
  STG(pB + hOffB,  ldbB8, 24576 + w1k);            // buf0.B1(0)
  if (nt > 1) {
    STG(pA + 128, ldaB8, 32768 + w1k);             // buf1.A0(1)
    STG(pB + 128, ldbB8, 49152 + w1k);             // buf1.B0(1)
    asm volatile("s_waitcnt vmcnt(4)" ::: "memory");
  } else {
    asm volatile("s_waitcnt vmcnt(0)" ::: "memory");
  }
  __builtin_amdgcn_s_barrier();

  for (int t = 0; t < nt; ++t) {
    const int bufS = (t & 1) << 15;
    const int obufS = bufS ^ 32768;
    const bool st1 = (t + 1 < nt), st2 = (t + 2 < nt);
    // P1 (0,0): stage A1(t+1), B1(t+1) -> other buffer
    DO_PHASE(0, 0,
      { if (st1) { STG(pA + 128 + hOffA, ldaB8, obufS + 8192 + w1k);
                   STG(pB + 128 + hOffB, ldbB8, obufS + 24576 + w1k); } },
      do {} while (0));
    // P2 (0,1): no stage
    DO_PHASE(0, 1, do {} while (0), do {} while (0));
    // P3 (1,0): stage A0(t+2) -> this buffer (A0 dead after P2)
    DO_PHASE(1, 0,
      { if (st2) STG(pA + 256, ldaB8, bufS + w1k); },
      do {} while (0));
    // P4 (1,1): stage B0(t+2) (B0 dead after P3); counted vmcnt
    DO_PHASE(1, 1,
      { if (st2) STG(pB + 256, ldbB8, bufS + 16384 + w1k); },
      { if (st2)      asm volatile("s_waitcnt vmcnt(4)" ::: "memory");
        else if (st1) asm volatile("s_waitcnt vmcnt(0)" ::: "memory"); });
    pA += 128; pB += 128;
  }

  // ---- epilogue ----
  const int rB = g4 * 4;
  if (EPI == 0) {
    short* C = (short*)Cv + (long long)bz * sC;
#pragma unroll
    for (int qn = 0; qn < 2; ++qn)
#pragma unroll
      for (int ni = 0; ni < 2; ++ni) {
        const int col = n0 + qn * 128 + wn * 32 + ni * 16 + l15;
        const float bv = X[col];
#pragma unroll
        for (int qm = 0; qm < 2; ++qm)
#pragma unroll
          for (int mi = 0; mi < 4; ++mi)
#pragma unroll
            for (int r = 0; r < 4; ++r) {
              const int row = m0 + qm * 128 + wm * 64 + mi * 16 + rB + r;
              C[(long long)row * ldc + col] = f2bf(acc[qm][qn][mi][ni][r] + bv);
            }
      }
  } else if (EPI == 1) {
    short* C = (short*)Cv + (long long)bz * sC;
#pragma unroll
    for (int qn = 0; qn < 2; ++qn)
#pragma unroll
      for (int ni = 0; ni < 2; ++ni) {
        const int col = n0 + qn * 128 + wn * 32 + ni * 16 + l15;
#pragma unroll
        for (int qm = 0; qm < 2; ++qm)
#pragma unroll
          for (int mi = 0; mi < 4; ++mi)
#pragma unroll
            for (int r = 0; r < 4; ++r) {
              const int row = m0 + qm * 128 + wm * 64 + mi * 16 + rB + r;
              C[(long long)row * ldc + col] = f2bf(acc[qm][qn][mi][ni][r] * scale);
            }
      }
  } else if (EPI == 2) {
    float* C = (float*)Cv + (long long)bz * sC;
    const float* Xb = X + (long long)bz * sX;
#pragma unroll
    for (int qn = 0; qn < 2; ++qn)
#pragma unroll
      for (int ni = 0; ni < 2; ++ni) {
        const int col = n0 + qn * 128 + wn * 32 + ni * 16 + l15;
#pragma unroll
        for (int qm = 0; qm < 2; ++qm)
#pragma unroll
          for (int mi = 0; mi < 4; ++mi)
#pragma unroll
            for (int r = 0; r < 4; ++r) {
              const int row = m0 + qm * 128 + wm * 64 + mi * 16 + rB + r;
              const long long idx = (long long)row * ldc + col;
              C[idx] = acc[qm][qn][mi][ni][r] + Xb[idx];
            }
      }
  } else {  // EPI == 3: C = V^T, [b][f=row][s], n = b*2048 + s
    short* C = (short*)Cv;
#pragma unroll
    for (int qn = 0; qn < 2; ++qn)
#pragma unroll
      for (int ni = 0; ni < 2; ++ni) {
        const int col = n0 + qn * 128 + wn * 32 + ni * 16 + l15;
        const int bb = col >> 11;
        const int s = col & 2047;
#pragma unroll
        for (int qm = 0; qm < 2; ++qm)
#pragma unroll
          for (int mi = 0; mi < 4; ++mi)
#pragma unroll
            for (int r = 0; r < 4; ++r) {
              const int row = m0 + qm * 128 + wm * 64 + mi * 16 + rB + r;
              C[(long long)bb * 2097152 + (long long)row * 2048 + s] =
                  f2bf(acc[qm][qn][mi][ni][r] + X[row]);
            }
      }
  }
}

// ---------------- row softmax over 2048 (in-place, bf16) ----------------
__global__ __launch_bounds__(256) void softmax_k(short* __restrict__ P) {
  __shared__ float redm[4];
  __shared__ float reds[4];
  const long long row = blockIdx.x;
  short* p = P + row * 2048;
  const int t = threadIdx.x;
  const int w = t >> 6, lane = t & 63;
  bf16x8 v = *(const bf16x8*)(p + t * 8);
  float f[8];
  float mx = -3.0e38f;
#pragma unroll
  for (int j = 0; j < 8; ++j) { f[j] = bf2f(v[j]); mx = fmaxf(mx, f[j]); }
#pragma unroll
  for (int o = 32; o > 0; o >>= 1) mx = fmaxf(mx, __shfl_xor(mx, o));
  if (lane == 0) redm[w] = mx;
  __syncthreads();
  mx = fmaxf(fmaxf(redm[0], redm[1]), fmaxf(redm[2], redm[3]));
  float s = 0.f;
#pragma unroll
  for (int j = 0; j < 8; ++j) { f[j] = __expf(f[j] - mx); s += f[j]; }
#pragma unroll
  for (int o = 32; o > 0; o >>= 1) s += __shfl_xor(s, o);
  if (lane == 0) reds[w] = s;
  __syncthreads();
  s = reds[0] + reds[1] + reds[2] + reds[3];
  const float inv = 1.0f / (s + 1e-6f);
  bf16x8 o8;
#pragma unroll
  for (int j = 0; j < 8; ++j) o8[j] = f2bf(f[j] * inv);
  *(bf16x8*)(p + t * 8) = o8;
}

extern "C" void kernel_launch(void* const* d_in, const int* in_sizes, int n_in,
                              void* d_out, int out_size, void* d_ws, size_t ws_size,
                              hipStream_t stream) {
  const float* x  = (const float*)d_in[0];
  const float* y  = (const float*)d_in[1];
  const float* Wq = (const float*)d_in[2];
  const float* bq = (const float*)d_in[3];
  const float* Wk = (const float*)d_in[4];
  const float* bk = (const float*)d_in[5];
  const float* Wv = (const float*)d_in[6];
  const float* bv = (const float*)d_in[7];
  float* out = (float*)d_out;

  const long long SD  = 2048LL * 1024;
  const long long BSD = 16LL * SD;
  const long long SS  = 2048LL * 2048;

  char* ws = (char*)d_ws;
  short* xb  = (short*)ws;                   // 67.1 MB
  short* yb  = xb + BSD;                     // 67.1 MB
  short* Sl  = (short*)ws;                   // 134.2 MB (aliases xb+yb; written after they die)
  short* Qb  = (short*)(ws + 134217728);     // 67.1 MB
  short* Kb  = Qb + BSD;                     // 67.1 MB
  short* Vt  = Kb + BSD;                     // 67.1 MB  [b][d][s]
  short* Wqt = Vt + BSD;                     // 2 MB each
  short* Wkt = Wqt + 1024 * 1024;
  short* Wvt = Wkt + 1024 * 1024;

  // 1) convert x, y to bf16
  cvt_k<<<2048, 256, 0, stream>>>(x, xb, (int)(BSD / 4));
  cvt_k<<<2048, 256, 0, stream>>>(y, yb, (int)(BSD / 4));

  // 2) transpose+convert weights
  cvtT_k<<<dim3(32, 32), 256, 0, stream>>>(Wq, Wqt);
  cvtT_k<<<dim3(32, 32), 256, 0, stream>>>(Wk, Wkt);
  cvtT_k<<<dim3(32, 32), 256, 0, stream>>>(Wv, Wvt);

  // 3) Q = xb @ Wq + bq   (M=32768, N=1024, K=1024)
  gemm8_k<0><<<dim3(4, 128, 1), 512, 0, stream>>>(
      xb, Wqt, Qb, bq, 1024, 1024, 1024, 1024, 0, 0, 0, 0, 1.f);
  // 4) K = yb @ Wk + bk
  gemm8_k<0><<<dim3(4, 128, 1), 512, 0, stream>>>(
      yb, Wkt, Kb, bk, 1024, 1024, 1024, 1024, 0, 0, 0, 0, 1.f);
  // 5) V^T directly: A = Wv^T (M=1024=f), Bt = yb (N=32768) -> Vt[b][f][s]
  gemm8_k<3><<<dim3(128, 4, 1), 512, 0, stream>>>(
      Wvt, yb, Vt, bv, 1024, 1024, 1024, 0, 0, 0, 0, 0, 1.f);

  // 6) logits = Q @ K^T / 32  (batched 16x: M=N=2048, K=1024) -> bf16
  gemm8_k<1><<<dim3(8, 8, 16), 512, 0, stream>>>(
      Qb, Kb, Sl, nullptr, 1024, 1024, 1024, 2048, SD, SD, SS, 0, 0.03125f);

  // 7) softmax rows (32768 rows of 2048), in-place
  softmax_k<<<32768, 256, 0, stream>>>(Sl);

  // 8) out = P @ V + x  (batched 16x: M=2048, N=1024, K=2048) -> f32
  gemm8_k<2><<<dim3(4, 8, 16), 512, 0, stream>>>(
      Sl, Vt, out, x, 2048, 2048, 2048, 1024, SS, SD, SD, SD, 1.f);

  (void)in_sizes; (void)n_in; (void)out_size; (void)ws_size;
}

// Round 4
// 752.924 us; speedup vs baseline: 1.3418x; 1.0630x over previous
//
#include <hip/hip_runtime.h>
#include <hip/hip_bf16.h>

typedef __attribute__((ext_vector_type(8))) short bf16x8;
typedef __attribute__((ext_vector_type(4))) float f32x4;

__device__ __forceinline__ float bf2f(short u) {
  union { unsigned int u; float f; } c;
  c.u = ((unsigned int)(unsigned short)u) << 16;
  return c.f;
}
__device__ __forceinline__ short f2bf(float f) {
  union { float f; unsigned int u; } c; c.f = f;
  unsigned int r = (c.u + 0x7fffu + ((c.u >> 16) & 1u)) >> 16;
  return (short)(unsigned short)r;
}

__device__ __forceinline__ void gload16(const void* g, void* l) {
  __builtin_amdgcn_global_load_lds(
      (const __attribute__((address_space(1))) unsigned int*)g,
      (__attribute__((address_space(3))) unsigned int*)l, 16, 0, 0);
}

// ---------------- fp32 -> bf16 convert ----------------
__global__ __launch_bounds__(256) void cvt_k(const float* __restrict__ in,
                                             short* __restrict__ out, int n4) {
  int i = blockIdx.x * blockDim.x + threadIdx.x;
  const int stride = gridDim.x * blockDim.x;
  for (; i < n4; i += stride) {
    float4 v = ((const float4*)in)[i];
    short4 o;
    o.x = f2bf(v.x); o.y = f2bf(v.y); o.z = f2bf(v.z); o.w = f2bf(v.w);
    ((short4*)out)[i] = o;
  }
}

// ---------------- W [1024][1024] f32 -> W^T bf16 ----------------
__global__ __launch_bounds__(256) void cvtT_k(const float* __restrict__ W,
                                              short* __restrict__ Wt) {
  __shared__ float tile[32][33];
  const int n0 = blockIdx.x * 32, k0 = blockIdx.y * 32;
  const int tr = threadIdx.x >> 5;
  const int tc = threadIdx.x & 31;
#pragma unroll
  for (int p = 0; p < 4; ++p)
    tile[p * 8 + tr][tc] = W[(long long)(k0 + p * 8 + tr) * 1024 + n0 + tc];
  __syncthreads();
#pragma unroll
  for (int p = 0; p < 4; ++p)
    Wt[(long long)(n0 + p * 8 + tr) * 1024 + k0 + tc] = f2bf(tile[tc][p * 8 + tr]);
}

// =====================================================================
// 256x256x64 snake-phase bf16 MFMA GEMM
//   C[m][n] = sum_k A[m][k] * Bt[n][k]
// 8 waves (2M x 4N), per-wave out 128x64. Per K-tile: 3 barrier-phases in
// snake quadrant order (0,0)->(0,1)->(1,1)+(1,0), each operand ds_read
// exactly once per K-tile (24 x ds_read_b128), double-buffered 128KiB LDS,
// counted vmcnt(4), XOR-16B-slot swizzle, setprio around MFMA clusters.
// EPI 0: bf16 out + bias[col]; 1: bf16 out*scale; 2: f32 out + X[idx];
// EPI 3: bf16 out to V^T layout [b][f=row][s], bias[row].
// =====================================================================

#define STG(sp, ld8, dOff) do { \
  gload16((sp), Ls + (dOff)); \
  gload16((const char*)(sp) + (ld8), Ls + (dOff) + 512); } while (0)

#define RD_A(QM) do { \
  _Pragma("unroll") \
  for (int mi = 0; mi < 4; ++mi) { \
    aR[mi][0] = *(const bf16x8*)(Ls + bufS + (QM)*8192 + arow + mi*1024 + aO0); \
    aR[mi][1] = *(const bf16x8*)(Ls + bufS + (QM)*8192 + arow + mi*1024 + aO1); \
  } } while (0)

#define RD_B(DST, QN) do { \
  _Pragma("unroll") \
  for (int ni = 0; ni < 2; ++ni) { \
    DST[ni][0] = *(const bf16x8*)(Ls + bufS + 16384 + (QN)*8192 + brow + ni*1024 + aO0); \
    DST[ni][1] = *(const bf16x8*)(Ls + bufS + 16384 + (QN)*8192 + brow + ni*1024 + aO1); \
  } } while (0)

#define SYNCIN do { \
  __builtin_amdgcn_sched_barrier(0); \
  __builtin_amdgcn_s_barrier(); \
  asm volatile("s_waitcnt lgkmcnt(0)" ::: "memory"); \
  __builtin_amdgcn_sched_barrier(0); \
  __builtin_amdgcn_s_setprio(1); } while (0)

#define SYNCOUT do { \
  __builtin_amdgcn_s_setprio(0); \
  __builtin_amdgcn_s_barrier(); } while (0)

#define MF16(ACCQ, BB) do { \
  _Pragma("unroll") \
  for (int mi = 0; mi < 4; ++mi) { \
    _Pragma("unroll") \
    for (int ni = 0; ni < 2; ++ni) { \
      ACCQ[mi][ni] = __builtin_amdgcn_mfma_f32_16x16x32_bf16(aR[mi][0], BB[ni][0], ACCQ[mi][ni], 0, 0, 0); \
      ACCQ[mi][ni] = __builtin_amdgcn_mfma_f32_16x16x32_bf16(aR[mi][1], BB[ni][1], ACCQ[mi][ni], 0, 0, 0); \
    } \
  } } while (0)

template<int EPI>
__global__ __launch_bounds__(512) void gemm8_k(
    const short* __restrict__ A, const short* __restrict__ Bt,
    void* __restrict__ Cv, const float* __restrict__ X,
    int K, int lda, int ldb, int ldc,
    long long sA, long long sB, long long sC, long long sX, float scale) {
  __shared__ __align__(16) short Ls[65536];   // 128 KiB

  const int lane = threadIdx.x & 63;
  const int w = threadIdx.x >> 6;       // 0..7
  const int wm = w >> 2, wn = w & 3;
  const int w1k = w * 1024;
  const int l15 = lane & 15;
  const int g4 = lane >> 4;             // 0..3
  const int p8 = lane & 7;
  const int r8 = lane >> 3;             // 0..7
  const int aO0 = (g4 ^ p8) << 3;       // kk=0 swizzled 16B-slot (shorts)
  const int aO1 = ((4 + g4) ^ p8) << 3; // kk=1
  const int arow = (wm * 64 + l15) * 64;
  const int brow = (wn * 32 + l15) * 64;

  const int bz = blockIdx.z;
  const int n0 = blockIdx.x * 256;
  const int m0 = blockIdx.y * 256;
  const int nt = K >> 6;

  const long long ldaB = 2LL * lda, ldbB = 2LL * ldb;
  const long long ldaB8 = 8 * ldaB, ldbB8 = 8 * ldbB;
  const long long hOffA = 128 * ldaB, hOffB = 128 * ldbB;

  // per-lane pre-swizzled staging source pointers (dest stays linear)
  const char* pA = (const char*)(A + (long long)bz * sA)
      + (long long)(m0 + w * 16 + r8) * ldaB + ((p8 ^ r8) << 4);
  const char* pB = (const char*)(Bt + (long long)bz * sB)
      + (long long)(n0 + w * 16 + r8) * ldbB + ((p8 ^ r8) << 4);

  f32x4 acc[2][2][4][2] = {};
  bf16x8 aR[4][2], bR0[2][2], bR1[2][2];

  // ---- prologue: tile0 all 4 halves + A0,B0 of tile1 ----
  STG(pA,          ldaB8, 0 + w1k);                // buf0.A0(0)
  STG(pA + hOffA,  ldaB8, 8192 + w1k);             // buf0.A1(0)
  STG(pB,          ldbB8, 16384 + w1k);            // buf0.B0(0)
  STG(pB + hOffB,  ldbB8, 24576 + w1k);            // buf0.B1(0)
  if (nt > 1) {
    STG(pA + 128, ldaB8, 32768 + w1k);             // buf1.A0(1)
    STG(pB + 128, ldbB8, 49152 + w1k);             // buf1.B0(1)
    asm volatile("s_waitcnt vmcnt(4)" ::: "memory");
  } else {
    asm volatile("s_waitcnt vmcnt(0)" ::: "memory");
  }
  __builtin_amdgcn_s_barrier();

  for (int t = 0; t < nt; ++t) {
    const int bufS = (t & 1) << 15;
    const int obufS = bufS ^ 32768;
    const bool st1 = (t + 1 < nt), st2 = (t + 2 < nt);

    // PH1 (0,0): read A0 + B0; stage A1(t+1), B1(t+1) -> other buffer
    RD_A(0); RD_B(bR0, 0);
    if (st1) { STG(pA + 128 + hOffA, ldaB8, obufS + 8192 + w1k);
               STG(pB + 128 + hOffB, ldbB8, obufS + 24576 + w1k); }
    SYNCIN;
    MF16(acc[0][0], bR0);
    SYNCOUT;

    // PH2 (0,1): read B1; stage A0(t+2) -> this buffer (A0 dead after PH1)
    RD_B(bR1, 1);
    if (st2) STG(pA + 256, ldaB8, bufS + w1k);
    SYNCIN;
    MF16(acc[0][1], bR1);
    SYNCOUT;

    // PH3 (1,1)+(1,0) merged: read A1; stage B0(t+2) (B0 LDS dead after PH1);
    // B0 operand comes from registers. Counted vmcnt once per tile.
    RD_A(1);
    if (st2) STG(pB + 256, ldbB8, bufS + 16384 + w1k);
    SYNCIN;
    MF16(acc[1][1], bR1);
    MF16(acc[1][0], bR0);
    __builtin_amdgcn_s_setprio(0);
    if (st2)      asm volatile("s_waitcnt vmcnt(4)" ::: "memory");
    else if (st1) asm volatile("s_waitcnt vmcnt(0)" ::: "memory");
    __builtin_amdgcn_s_barrier();

    pA += 128; pB += 128;
  }

  // ---- epilogue ----
  const int rB = g4 * 4;
  if (EPI == 0) {
    short* C = (short*)Cv + (long long)bz * sC;
#pragma unroll
    for (int qn = 0; qn < 2; ++qn)
#pragma unroll
      for (int ni = 0; ni < 2; ++ni) {
        const int col = n0 + qn * 128 + wn * 32 + ni * 16 + l15;
        const float bv = X[col];
#pragma unroll
        for (int qm = 0; qm < 2; ++qm)
#pragma unroll
          for (int mi = 0; mi < 4; ++mi)
#pragma unroll
            for (int r = 0; r < 4; ++r) {
              const int row = m0 + qm * 128 + wm * 64 + mi * 16 + rB + r;
              C[(long long)row * ldc + col] = f2bf(acc[qm][qn][mi][ni][r] + bv);
            }
      }
  } else if (EPI == 1) {
    short* C = (short*)Cv + (long long)bz * sC;
#pragma unroll
    for (int qn = 0; qn < 2; ++qn)
#pragma unroll
      for (int ni = 0; ni < 2; ++ni) {
        const int col = n0 + qn * 128 + wn * 32 + ni * 16 + l15;
#pragma unroll
        for (int qm = 0; qm < 2; ++qm)
#pragma unroll
          for (int mi = 0; mi < 4; ++mi)
#pragma unroll
            for (int r = 0; r < 4; ++r) {
              const int row = m0 + qm * 128 + wm * 64 + mi * 16 + rB + r;
              C[(long long)row * ldc + col] = f2bf(acc[qm][qn][mi][ni][r] * scale);
            }
      }
  } else if (EPI == 2) {
    float* C = (float*)Cv + (long long)bz * sC;
    const float* Xb = X + (long long)bz * sX;
#pragma unroll
    for (int qn = 0; qn < 2; ++qn)
#pragma unroll
      for (int ni = 0; ni < 2; ++ni) {
        const int col = n0 + qn * 128 + wn * 32 + ni * 16 + l15;
#pragma unroll
        for (int qm = 0; qm < 2; ++qm)
#pragma unroll
          for (int mi = 0; mi < 4; ++mi)
#pragma unroll
            for (int r = 0; r < 4; ++r) {
              const int row = m0 + qm * 128 + wm * 64 + mi * 16 + rB + r;
              const long long idx = (long long)row * ldc + col;
              C[idx] = acc[qm][qn][mi][ni][r] + Xb[idx];
            }
      }
  } else {  // EPI == 3: C = V^T, [b][f=row][s], n = b*2048 + s
    short* C = (short*)Cv;
#pragma unroll
    for (int qn = 0; qn < 2; ++qn)
#pragma unroll
      for (int ni = 0; ni < 2; ++ni) {
        const int col = n0 + qn * 128 + wn * 32 + ni * 16 + l15;
        const int bb = col >> 11;
        const int s = col & 2047;
#pragma unroll
        for (int qm = 0; qm < 2; ++qm)
#pragma unroll
          for (int mi = 0; mi < 4; ++mi)
#pragma unroll
            for (int r = 0; r < 4; ++r) {
              const int row = m0 + qm * 128 + wm * 64 + mi * 16 + rB + r;
              C[(long long)bb * 2097152 + (long long)row * 2048 + s] =
                  f2bf(acc[qm][qn][mi][ni][r] + X[row]);
            }
      }
  }
}

// ---------------- row softmax over 2048 (in-place, bf16) ----------------
__global__ __launch_bounds__(256) void softmax_k(short* __restrict__ P) {
  __shared__ float redm[4];
  __shared__ float reds[4];
  const long long row = blockIdx.x;
  short* p = P + row * 2048;
  const int t = threadIdx.x;
  const int w = t >> 6, lane = t & 63;
  bf16x8 v = *(const bf16x8*)(p + t * 8);
  float f[8];
  float mx = -3.0e38f;
#pragma unroll
  for (int j = 0; j < 8; ++j) { f[j] = bf2f(v[j]); mx = fmaxf(mx, f[j]); }
#pragma unroll
  for (int o = 32; o > 0; o >>= 1) mx = fmaxf(mx, __shfl_xor(mx, o));
  if (lane == 0) redm[w] = mx;
  __syncthreads();
  mx = fmaxf(fmaxf(redm[0], redm[1]), fmaxf(redm[2], redm[3]));
  float s = 0.f;
#pragma unroll
  for (int j = 0; j < 8; ++j) { f[j] = __expf(f[j] - mx); s += f[j]; }
#pragma unroll
  for (int o = 32; o > 0; o >>= 1) s += __shfl_xor(s, o);
  if (lane == 0) reds[w] = s;
  __syncthreads();
  s = reds[0] + reds[1] + reds[2] + reds[3];
  const float inv = 1.0f / (s + 1e-6f);
  bf16x8 o8;
#pragma unroll
  for (int j = 0; j < 8; ++j) o8[j] = f2bf(f[j] * inv);
  *(bf16x8*)(p + t * 8) = o8;
}

extern "C" void kernel_launch(void* const* d_in, const int* in_sizes, int n_in,
                              void* d_out, int out_size, void* d_ws, size_t ws_size,
                              hipStream_t stream) {
  const float* x  = (const float*)d_in[0];
  const float* y  = (const float*)d_in[1];
  const float* Wq = (const float*)d_in[2];
  const float* bq = (const float*)d_in[3];
  const float* Wk = (const float*)d_in[4];
  const float* bk = (const float*)d_in[5];
  const float* Wv = (const float*)d_in[6];
  const float* bv = (const float*)d_in[7];
  float* out = (float*)d_out;

  const long long SD  = 2048LL * 1024;
  const long long BSD = 16LL * SD;
  const long long SS  = 2048LL * 2048;

  char* ws = (char*)d_ws;
  short* xb  = (short*)ws;                   // 67.1 MB
  short* yb  = xb + BSD;                     // 67.1 MB
  short* Sl  = (short*)ws;                   // 134.2 MB (aliases xb+yb; written after they die)
  short* Qb  = (short*)(ws + 134217728);     // 67.1 MB
  short* Kb  = Qb + BSD;                     // 67.1 MB
  short* Vt  = Kb + BSD;                     // 67.1 MB  [b][d][s]
  short* Wqt = Vt + BSD;                     // 2 MB each
  short* Wkt = Wqt + 1024 * 1024;
  short* Wvt = Wkt + 1024 * 1024;

  // 1) convert x, y to bf16
  cvt_k<<<2048, 256, 0, stream>>>(x, xb, (int)(BSD / 4));
  cvt_k<<<2048, 256, 0, stream>>>(y, yb, (int)(BSD / 4));

  // 2) transpose+convert weights
  cvtT_k<<<dim3(32, 32), 256, 0, stream>>>(Wq, Wqt);
  cvtT_k<<<dim3(32, 32), 256, 0, stream>>>(Wk, Wkt);
  cvtT_k<<<dim3(32, 32), 256, 0, stream>>>(Wv, Wvt);

  // 3) Q = xb @ Wq + bq   (M=32768, N=1024, K=1024)
  gemm8_k<0><<<dim3(4, 128, 1), 512, 0, stream>>>(
      xb, Wqt, Qb, bq, 1024, 1024, 1024, 1024, 0, 0, 0, 0, 1.f);
  // 4) K = yb @ Wk + bk
  gemm8_k<0><<<dim3(4, 128, 1), 512, 0, stream>>>(
      yb, Wkt, Kb, bk, 1024, 1024, 1024, 1024, 0, 0, 0, 0, 1.f);
  // 5) V^T directly: A = Wv^T (M=1024=f), Bt = yb (N=32768) -> Vt[b][f][s]
  gemm8_k<3><<<dim3(128, 4, 1), 512, 0, stream>>>(
      Wvt, yb, Vt, bv, 1024, 1024, 1024, 0, 0, 0, 0, 0, 1.f);

  // 6) logits = Q @ K^T / 32  (batched 16x: M=N=2048, K=1024) -> bf16
  gemm8_k<1><<<dim3(8, 8, 16), 512, 0, stream>>>(
      Qb, Kb, Sl, nullptr, 1024, 1024, 1024, 2048, SD, SD, SS, 0, 0.03125f);

  // 7) softmax rows (32768 rows of 2048), in-place
  softmax_k<<<32768, 256, 0, stream>>>(Sl);

  // 8) out = P @ V + x  (batched 16x: M=2048, N=1024, K=2048) -> f32
  gemm8_k<2><<<dim3(4, 8, 16), 512, 0, stream>>>(
      Sl, Vt, out, x, 2048, 2048, 2048, 1024, SS, SD, SD, SD, 1.f);

  (void)in_sizes; (void)n_in; (void)out_size; (void)ws_size;
}

// Round 5
// 728.321 us; speedup vs baseline: 1.3871x; 1.0338x over previous
//
#include <hip/hip_runtime.h>
#include <hip/hip_bf16.h>

typedef __attribute__((ext_vector_type(8))) short bf16x8;
typedef __attribute__((ext_vector_type(4))) float f32x4;

__device__ __forceinline__ float bf2f(short u) {
  union { unsigned int u; float f; } c;
  c.u = ((unsigned int)(unsigned short)u) << 16;
  return c.f;
}
__device__ __forceinline__ short f2bf(float f) {
  union { float f; unsigned int u; } c; c.f = f;
  unsigned int r = (c.u + 0x7fffu + ((c.u >> 16) & 1u)) >> 16;
  return (short)(unsigned short)r;
}

__device__ __forceinline__ void gload16(const void* g, void* l) {
  __builtin_amdgcn_global_load_lds(
      (const __attribute__((address_space(1))) unsigned int*)g,
      (__attribute__((address_space(3))) unsigned int*)l, 16, 0, 0);
}

// ---------------- fp32 -> bf16 convert ----------------
__global__ __launch_bounds__(256) void cvt_k(const float* __restrict__ in,
                                             short* __restrict__ out, int n4) {
  int i = blockIdx.x * blockDim.x + threadIdx.x;
  const int stride = gridDim.x * blockDim.x;
  for (; i < n4; i += stride) {
    float4 v = ((const float4*)in)[i];
    short4 o;
    o.x = f2bf(v.x); o.y = f2bf(v.y); o.z = f2bf(v.z); o.w = f2bf(v.w);
    ((short4*)out)[i] = o;
  }
}

// ---------------- W [1024][1024] f32 -> W^T bf16 ----------------
__global__ __launch_bounds__(256) void cvtT_k(const float* __restrict__ W,
                                              short* __restrict__ Wt) {
  __shared__ float tile[32][33];
  const int n0 = blockIdx.x * 32, k0 = blockIdx.y * 32;
  const int tr = threadIdx.x >> 5;
  const int tc = threadIdx.x & 31;
#pragma unroll
  for (int p = 0; p < 4; ++p)
    tile[p * 8 + tr][tc] = W[(long long)(k0 + p * 8 + tr) * 1024 + n0 + tc];
  __syncthreads();
#pragma unroll
  for (int p = 0; p < 4; ++p)
    Wt[(long long)(n0 + p * 8 + tr) * 1024 + k0 + tc] = f2bf(tile[tc][p * 8 + tr]);
}

// =====================================================================
// 256x256x64 snake-phase bf16 MFMA GEMM + XCD-aware block swizzle
//   C[m][n] = sum_k A[m][k] * Bt[n][k]
// 8 waves (2M x 4N), per-wave out 128x64. Per K-tile: 3 barrier-phases in
// snake quadrant order (0,0)->(0,1)->(1,1)+(1,0), 24 ds_read_b128/tile,
// double-buffered 128KiB LDS, counted vmcnt(4), XOR-16B-slot swizzle.
// Block swizzle: lid' = (lid%8)*(nwg/8)+lid/8 gives each XCD a contiguous
// chunk of the logical grid so panel-sharing blocks hit the same L2.
// EPI 0: bf16 out + bias[col]; 1: bf16 out*scale; 2: f32 out + X[idx];
// EPI 3: bf16 out to V^T layout [b][f=row][s], bias[row].
// =====================================================================

#define STG(sp, ld8, dOff) do { \
  gload16((sp), Ls + (dOff)); \
  gload16((const char*)(sp) + (ld8), Ls + (dOff) + 512); } while (0)

#define RD_A(QM) do { \
  _Pragma("unroll") \
  for (int mi = 0; mi < 4; ++mi) { \
    aR[mi][0] = *(const bf16x8*)(Ls + bufS + (QM)*8192 + arow + mi*1024 + aO0); \
    aR[mi][1] = *(const bf16x8*)(Ls + bufS + (QM)*8192 + arow + mi*1024 + aO1); \
  } } while (0)

#define RD_B(DST, QN) do { \
  _Pragma("unroll") \
  for (int ni = 0; ni < 2; ++ni) { \
    DST[ni][0] = *(const bf16x8*)(Ls + bufS + 16384 + (QN)*8192 + brow + ni*1024 + aO0); \
    DST[ni][1] = *(const bf16x8*)(Ls + bufS + 16384 + (QN)*8192 + brow + ni*1024 + aO1); \
  } } while (0)

#define SYNCIN do { \
  __builtin_amdgcn_sched_barrier(0); \
  __builtin_amdgcn_s_barrier(); \
  asm volatile("s_waitcnt lgkmcnt(0)" ::: "memory"); \
  __builtin_amdgcn_sched_barrier(0); \
  __builtin_amdgcn_s_setprio(1); } while (0)

#define SYNCOUT do { \
  __builtin_amdgcn_s_setprio(0); \
  __builtin_amdgcn_s_barrier(); } while (0)

#define MF16(ACCQ, BB) do { \
  _Pragma("unroll") \
  for (int mi = 0; mi < 4; ++mi) { \
    _Pragma("unroll") \
    for (int ni = 0; ni < 2; ++ni) { \
      ACCQ[mi][ni] = __builtin_amdgcn_mfma_f32_16x16x32_bf16(aR[mi][0], BB[ni][0], ACCQ[mi][ni], 0, 0, 0); \
      ACCQ[mi][ni] = __builtin_amdgcn_mfma_f32_16x16x32_bf16(aR[mi][1], BB[ni][1], ACCQ[mi][ni], 0, 0, 0); \
    } \
  } } while (0)

template<int EPI>
__global__ __launch_bounds__(512) void gemm8_k(
    const short* __restrict__ A, const short* __restrict__ Bt,
    void* __restrict__ Cv, const float* __restrict__ X,
    int K, int lda, int ldb, int ldc,
    long long sA, long long sB, long long sC, long long sX, float scale) {
  __shared__ __align__(16) short Ls[65536];   // 128 KiB

  const int lane = threadIdx.x & 63;
  const int w = threadIdx.x >> 6;       // 0..7
  const int wm = w >> 2, wn = w & 3;
  const int w1k = w * 1024;
  const int l15 = lane & 15;
  const int g4 = lane >> 4;             // 0..3
  const int p8 = lane & 7;
  const int r8 = lane >> 3;             // 0..7
  const int aO0 = (g4 ^ p8) << 3;       // kk=0 swizzled 16B-slot (shorts)
  const int aO1 = ((4 + g4) ^ p8) << 3; // kk=1
  const int arow = (wm * 64 + l15) * 64;
  const int brow = (wn * 32 + l15) * 64;

  // ---- XCD-aware bijective block swizzle (requires nwg % 8 == 0) ----
  const int gx = gridDim.x, gy = gridDim.y;
  const int nwg = gx * gy * gridDim.z;
  int lid = blockIdx.x + gx * (blockIdx.y + gy * blockIdx.z);
  lid = (lid & 7) * (nwg >> 3) + (lid >> 3);
  const int bx = lid % gx;
  const int rem = lid / gx;
  const int by = rem % gy;
  const int bz = rem / gy;

  const int n0 = bx * 256;
  const int m0 = by * 256;
  const int nt = K >> 6;

  const long long ldaB = 2LL * lda, ldbB = 2LL * ldb;
  const long long ldaB8 = 8 * ldaB, ldbB8 = 8 * ldbB;
  const long long hOffA = 128 * ldaB, hOffB = 128 * ldbB;

  // per-lane pre-swizzled staging source pointers (dest stays linear)
  const char* pA = (const char*)(A + (long long)bz * sA)
      + (long long)(m0 + w * 16 + r8) * ldaB + ((p8 ^ r8) << 4);
  const char* pB = (const char*)(Bt + (long long)bz * sB)
      + (long long)(n0 + w * 16 + r8) * ldbB + ((p8 ^ r8) << 4);

  f32x4 acc[2][2][4][2] = {};
  bf16x8 aR[4][2], bR0[2][2], bR1[2][2];

  // ---- prologue: tile0 all 4 halves + A0,B0 of tile1 ----
  STG(pA,          ldaB8, 0 + w1k);                // buf0.A0(0)
  STG(pA + hOffA,  ldaB8, 8192 + w1k);             // buf0.A1(0)
  STG(pB,          ldbB8, 16384 + w1k);            // buf0.B0(0)
  STG(pB + hOffB,  ldbB8, 24576 + w1k);            // buf0.B1(0)
  if (nt > 1) {
    STG(pA + 128, ldaB8, 32768 + w1k);             // buf1.A0(1)
    STG(pB + 128, ldbB8, 49152 + w1k);             // buf1.B0(1)
    asm volatile("s_waitcnt vmcnt(4)" ::: "memory");
  } else {
    asm volatile("s_waitcnt vmcnt(0)" ::: "memory");
  }
  __builtin_amdgcn_s_barrier();

  for (int t = 0; t < nt; ++t) {
    const int bufS = (t & 1) << 15;
    const int obufS = bufS ^ 32768;
    const bool st1 = (t + 1 < nt), st2 = (t + 2 < nt);

    // PH1 (0,0): read A0 + B0; stage A1(t+1), B1(t+1) -> other buffer
    RD_A(0); RD_B(bR0, 0);
    if (st1) { STG(pA + 128 + hOffA, ldaB8, obufS + 8192 + w1k);
               STG(pB + 128 + hOffB, ldbB8, obufS + 24576 + w1k); }
    SYNCIN;
    MF16(acc[0][0], bR0);
    SYNCOUT;

    // PH2 (0,1): read B1; stage A0(t+2) -> this buffer (A0 dead after PH1)
    RD_B(bR1, 1);
    if (st2) STG(pA + 256, ldaB8, bufS + w1k);
    SYNCIN;
    MF16(acc[0][1], bR1);
    SYNCOUT;

    // PH3 (1,1)+(1,0) merged: read A1; stage B0(t+2) (B0 LDS dead after PH1);
    // B0 operand comes from registers. Counted vmcnt once per tile.
    RD_A(1);
    if (st2) STG(pB + 256, ldbB8, bufS + 16384 + w1k);
    SYNCIN;
    MF16(acc[1][1], bR1);
    MF16(acc[1][0], bR0);
    __builtin_amdgcn_s_setprio(0);
    if (st2)      asm volatile("s_waitcnt vmcnt(4)" ::: "memory");
    else if (st1) asm volatile("s_waitcnt vmcnt(0)" ::: "memory");
    __builtin_amdgcn_s_barrier();

    pA += 128; pB += 128;
  }

  // ---- epilogue ----
  const int rB = g4 * 4;
  if (EPI == 0) {
    short* C = (short*)Cv + (long long)bz * sC;
#pragma unroll
    for (int qn = 0; qn < 2; ++qn)
#pragma unroll
      for (int ni = 0; ni < 2; ++ni) {
        const int col = n0 + qn * 128 + wn * 32 + ni * 16 + l15;
        const float bv = X[col];
#pragma unroll
        for (int qm = 0; qm < 2; ++qm)
#pragma unroll
          for (int mi = 0; mi < 4; ++mi)
#pragma unroll
            for (int r = 0; r < 4; ++r) {
              const int row = m0 + qm * 128 + wm * 64 + mi * 16 + rB + r;
              C[(long long)row * ldc + col] = f2bf(acc[qm][qn][mi][ni][r] + bv);
            }
      }
  } else if (EPI == 1) {
    short* C = (short*)Cv + (long long)bz * sC;
#pragma unroll
    for (int qn = 0; qn < 2; ++qn)
#pragma unroll
      for (int ni = 0; ni < 2; ++ni) {
        const int col = n0 + qn * 128 + wn * 32 + ni * 16 + l15;
#pragma unroll
        for (int qm = 0; qm < 2; ++qm)
#pragma unroll
          for (int mi = 0; mi < 4; ++mi)
#pragma unroll
            for (int r = 0; r < 4; ++r) {
              const int row = m0 + qm * 128 + wm * 64 + mi * 16 + rB + r;
              C[(long long)row * ldc + col] = f2bf(acc[qm][qn][mi][ni][r] * scale);
            }
      }
  } else if (EPI == 2) {
    float* C = (float*)Cv + (long long)bz * sC;
    const float* Xb = X + (long long)bz * sX;
#pragma unroll
    for (int qn = 0; qn < 2; ++qn)
#pragma unroll
      for (int ni = 0; ni < 2; ++ni) {
        const int col = n0 + qn * 128 + wn * 32 + ni * 16 + l15;
#pragma unroll
        for (int qm = 0; qm < 2; ++qm)
#pragma unroll
          for (int mi = 0; mi < 4; ++mi)
#pragma unroll
            for (int r = 0; r < 4; ++r) {
              const int row = m0 + qm * 128 + wm * 64 + mi * 16 + rB + r;
              const long long idx = (long long)row * ldc + col;
              C[idx] = acc[qm][qn][mi][ni][r] + Xb[idx];
            }
      }
  } else {  // EPI == 3: C = V^T, [b][f=row][s], n = b*2048 + s
    short* C = (short*)Cv;
#pragma unroll
    for (int qn = 0; qn < 2; ++qn)
#pragma unroll
      for (int ni = 0; ni < 2; ++ni) {
        const int col = n0 + qn * 128 + wn * 32 + ni * 16 + l15;
        const int bb = col >> 11;
        const int s = col & 2047;
#pragma unroll
        for (int qm = 0; qm < 2; ++qm)
#pragma unroll
          for (int mi = 0; mi < 4; ++mi)
#pragma unroll
            for (int r = 0; r < 4; ++r) {
              const int row = m0 + qm * 128 + wm * 64 + mi * 16 + rB + r;
              C[(long long)bb * 2097152 + (long long)row * 2048 + s] =
                  f2bf(acc[qm][qn][mi][ni][r] + X[row]);
            }
      }
  }
}

// ---------------- row softmax over 2048 (in-place, bf16) ----------------
__global__ __launch_bounds__(256) void softmax_k(short* __restrict__ P) {
  __shared__ float redm[4];
  __shared__ float reds[4];
  const long long row = blockIdx.x;
  short* p = P + row * 2048;
  const int t = threadIdx.x;
  const int w = t >> 6, lane = t & 63;
  bf16x8 v = *(const bf16x8*)(p + t * 8);
  float f[8];
  float mx = -3.0e38f;
#pragma unroll
  for (int j = 0; j < 8; ++j) { f[j] = bf2f(v[j]); mx = fmaxf(mx, f[j]); }
#pragma unroll
  for (int o = 32; o > 0; o >>= 1) mx = fmaxf(mx, __shfl_xor(mx, o));
  if (lane == 0) redm[w] = mx;
  __syncthreads();
  mx = fmaxf(fmaxf(redm[0], redm[1]), fmaxf(redm[2], redm[3]));
  float s = 0.f;
#pragma unroll
  for (int j = 0; j < 8; ++j) { f[j] = __expf(f[j] - mx); s += f[j]; }
#pragma unroll
  for (int o = 32; o > 0; o >>= 1) s += __shfl_xor(s, o);
  if (lane == 0) reds[w] = s;
  __syncthreads();
  s = reds[0] + reds[1] + reds[2] + reds[3];
  const float inv = 1.0f / (s + 1e-6f);
  bf16x8 o8;
#pragma unroll
  for (int j = 0; j < 8; ++j) o8[j] = f2bf(f[j] * inv);
  *(bf16x8*)(p + t * 8) = o8;
}

extern "C" void kernel_launch(void* const* d_in, const int* in_sizes, int n_in,
                              void* d_out, int out_size, void* d_ws, size_t ws_size,
                              hipStream_t stream) {
  const float* x  = (const float*)d_in[0];
  const float* y  = (const float*)d_in[1];
  const float* Wq = (const float*)d_in[2];
  const float* bq = (const float*)d_in[3];
  const float* Wk = (const float*)d_in[4];
  const float* bk = (const float*)d_in[5];
  const float* Wv = (const float*)d_in[6];
  const float* bv = (const float*)d_in[7];
  float* out = (float*)d_out;

  const long long SD  = 2048LL * 1024;
  const long long BSD = 16LL * SD;
  const long long SS  = 2048LL * 2048;

  char* ws = (char*)d_ws;
  short* xb  = (short*)ws;                   // 67.1 MB
  short* yb  = xb + BSD;                     // 67.1 MB
  short* Sl  = (short*)ws;                   // 134.2 MB (aliases xb+yb; written after they die)
  short* Qb  = (short*)(ws + 134217728);     // 67.1 MB
  short* Kb  = Qb + BSD;                     // 67.1 MB
  short* Vt  = Kb + BSD;                     // 67.1 MB  [b][d][s]
  short* Wqt = Vt + BSD;                     // 2 MB each
  short* Wkt = Wqt + 1024 * 1024;
  short* Wvt = Wkt + 1024 * 1024;

  // 1) convert x, y to bf16
  cvt_k<<<2048, 256, 0, stream>>>(x, xb, (int)(BSD / 4));
  cvt_k<<<2048, 256, 0, stream>>>(y, yb, (int)(BSD / 4));

  // 2) transpose+convert weights
  cvtT_k<<<dim3(32, 32), 256, 0, stream>>>(Wq, Wqt);
  cvtT_k<<<dim3(32, 32), 256, 0, stream>>>(Wk, Wkt);
  cvtT_k<<<dim3(32, 32), 256, 0, stream>>>(Wv, Wvt);

  // 3) Q = xb @ Wq + bq   (M=32768, N=1024, K=1024)
  gemm8_k<0><<<dim3(4, 128, 1), 512, 0, stream>>>(
      xb, Wqt, Qb, bq, 1024, 1024, 1024, 1024, 0, 0, 0, 0, 1.f);
  // 4) K = yb @ Wk + bk
  gemm8_k<0><<<dim3(4, 128, 1), 512, 0, stream>>>(
      yb, Wkt, Kb, bk, 1024, 1024, 1024, 1024, 0, 0, 0, 0, 1.f);
  // 5) V^T directly: A = Wv^T (M=1024=f), Bt = yb (N=32768) -> Vt[b][f][s]
  gemm8_k<3><<<dim3(128, 4, 1), 512, 0, stream>>>(
      Wvt, yb, Vt, bv, 1024, 1024, 1024, 0, 0, 0, 0, 0, 1.f);

  // 6) logits = Q @ K^T / 32  (batched 16x: M=N=2048, K=1024) -> bf16
  gemm8_k<1><<<dim3(8, 8, 16), 512, 0, stream>>>(
      Qb, Kb, Sl, nullptr, 1024, 1024, 1024, 2048, SD, SD, SS, 0, 0.03125f);

  // 7) softmax rows (32768 rows of 2048), in-place
  softmax_k<<<32768, 256, 0, stream>>>(Sl);

  // 8) out = P @ V + x  (batched 16x: M=2048, N=1024, K=2048) -> f32
  gemm8_k<2><<<dim3(4, 8, 16), 512, 0, stream>>>(
      Sl, Vt, out, x, 2048, 2048, 2048, 1024, SS, SD, SD, SD, 1.f);

  (void)in_sizes; (void)n_in; (void)out_size; (void)ws_size;
}